// Round 7
// baseline (106.584 us; speedup 1.0000x reference)
//
#include <hip/hip_runtime.h>

#define LOG2E 1.4426950408889634f

typedef __attribute__((ext_vector_type(8))) short short8;
typedef __attribute__((ext_vector_type(4))) float f32x4;

union AF { unsigned u[4]; short8 v; };
union BB { uint4 q; short8 v; };

__device__ __forceinline__ unsigned short f2bf(float f) {
  unsigned int u = __float_as_uint(f);
  u = (u + 0x7fffu + ((u >> 16) & 1u)) >> 16;   // RNE, finite inputs only
  return (unsigned short)u;
}

// ---------------------------------------------------------------------------
// Kernel 1: f = X @ W^T + b  (fp32 SGEMM, 128x128 tile, 8x8/thread)
// Emits: ft (bf16, layout [b][n/16][h][c][n%16]) and s_src/s_dst ([b][h][n],
// f32, PRE-SCALED by log2(e) so k2 can use raw v_exp_f32).
// ---------------------------------------------------------------------------
__global__ __launch_bounds__(256) void gat_k1(
    const float* __restrict__ X, const float* __restrict__ W,
    const float* __restrict__ bias, const float* __restrict__ a,
    unsigned short* __restrict__ ft, float* __restrict__ ssrc,
    float* __restrict__ sdst)
{
  __shared__ float Xs[8][128];
  __shared__ float Ws[8][128];
  const int tid = threadIdx.x;
  const int tx = tid & 15, ty = tid >> 4;
  const int m0 = blockIdx.x * 128;
  const int c0 = blockIdx.y * 128;

  float acc[8][8];
#pragma unroll
  for (int r = 0; r < 8; ++r)
#pragma unroll
    for (int j = 0; j < 8; ++j) acc[r][j] = 0.f;

  const int lrow = tid >> 1;
  const int kk0 = (tid & 1) * 4;
  const float* Xp = X + (size_t)(m0 + lrow) * 256 + kk0;
  const float* Wp = W + (size_t)(c0 + lrow) * 256 + kk0;

  for (int kc = 0; kc < 256; kc += 8) {
    float4 xv = *(const float4*)(Xp + kc);
    float4 wv = *(const float4*)(Wp + kc);
    __syncthreads();
    Xs[kk0 + 0][lrow] = xv.x; Xs[kk0 + 1][lrow] = xv.y;
    Xs[kk0 + 2][lrow] = xv.z; Xs[kk0 + 3][lrow] = xv.w;
    Ws[kk0 + 0][lrow] = wv.x; Ws[kk0 + 1][lrow] = wv.y;
    Ws[kk0 + 2][lrow] = wv.z; Ws[kk0 + 3][lrow] = wv.w;
    __syncthreads();
#pragma unroll
    for (int kk = 0; kk < 8; ++kk) {
      float av[8], wv8[8];
#pragma unroll
      for (int r = 0; r < 8; ++r) av[r] = Xs[kk][ty * 8 + r];
#pragma unroll
      for (int j = 0; j < 8; ++j) wv8[j] = Ws[kk][tx * 8 + j];
#pragma unroll
      for (int r = 0; r < 8; ++r)
#pragma unroll
        for (int j = 0; j < 8; ++j) acc[r][j] = fmaf(av[r], wv8[j], acc[r][j]);
    }
  }

  const int b = m0 >> 11;
  const int nloc0 = (m0 & 2047) + ty * 8;
  const int cg0 = c0 + tx * 8;
  const int h = cg0 >> 6;
  const int cb = cg0 & 63;

  float bv[8], av_s[8], av_d[8];
#pragma unroll
  for (int j = 0; j < 8; ++j) {
    bv[j]   = bias[cg0 + j];
    av_s[j] = a[h * 128 + cb + j];
    av_d[j] = a[h * 128 + 64 + cb + j];
  }
#pragma unroll
  for (int r = 0; r < 8; ++r)
#pragma unroll
    for (int j = 0; j < 8; ++j) acc[r][j] += bv[j];

  const int jt = nloc0 >> 4;
  const int ni = nloc0 & 15;
#pragma unroll
  for (int j = 0; j < 8; ++j) {
    unsigned int u[4];
#pragma unroll
    for (int q = 0; q < 4; ++q) {
      unsigned int lo = f2bf(acc[2 * q + 0][j]);
      unsigned int hi = f2bf(acc[2 * q + 1][j]);
      u[q] = lo | (hi << 16);
    }
    size_t off = ((((size_t)b * 128 + jt) * 4 + h) * 64 + (cb + j)) * 16 + ni;
    *(uint4*)(ft + off) = make_uint4(u[0], u[1], u[2], u[3]);
  }

  float sp[8], dp[8];
#pragma unroll
  for (int r = 0; r < 8; ++r) {
    float s = 0.f, d = 0.f;
#pragma unroll
    for (int j = 0; j < 8; ++j) {
      s = fmaf(acc[r][j], av_s[j], s);
      d = fmaf(acc[r][j], av_d[j], d);
    }
    sp[r] = s; dp[r] = d;
  }
#pragma unroll
  for (int off = 1; off < 8; off <<= 1) {
#pragma unroll
    for (int r = 0; r < 8; ++r) {
      sp[r] += __shfl_xor(sp[r], off);
      dp[r] += __shfl_xor(dp[r], off);
    }
  }
  if ((tx & 7) == 0) {
    float* sb = ssrc + ((size_t)b * 4 + h) * 2048 + nloc0;
    float* db = sdst + ((size_t)b * 4 + h) * 2048 + nloc0;
#pragma unroll
    for (int r = 0; r < 8; ++r) { sb[r] = sp[r] * LOG2E; db[r] = dp[r] * LOG2E; }
  }
}

// ---------------------------------------------------------------------------
// Kernel 2: fused mask + leaky-relu + softmax + PV (bf16 MFMA 16x16x32)
// Grid 1024 blocks (b = idx&7 XCD-pinned, itile = idx>>3, 16 i-rows).
// 512 thr = 8 waves = (head h, j-half p). 32 steps of 32 j's per wave.
// SOFTWARE PIPELINE: B-fragments 2-deep register prefetch (named A/B stages),
// mask-word + sd pair 1 step ahead, tree-summed e's, dual lsum accumulators.
// Zero barriers in main loop. launch_bounds(512,5) gives the register room
// R6's (512,8)/32-VGPR build lacked (that build serialized every load).
// ---------------------------------------------------------------------------
__global__ __launch_bounds__(512, 5) void gat_k2(
    const int* __restrict__ adj, const unsigned short* __restrict__ ft,
    const float* __restrict__ ssrc, const float* __restrict__ sdst,
    float* __restrict__ out)
{
  __shared__ __align__(16) unsigned char lds[37120];  // sd 32KB | Aw [64][17] u32
  float* sd = (float*)lds;                            // [4][2048] f32
  unsigned* Aw = (unsigned*)(lds + 32768);            // [64][17] u32

  const int tid = threadIdx.x;
  const int b = blockIdx.x & 7;
  const int itile = blockIdx.x >> 3;     // 0..127
  const int i0 = itile * 16;
  const int w = tid >> 6;
  const int h = w >> 1;                  // head
  const int p = w & 1;                   // j-half
  const int lane = tid & 63;
  const int i_l = lane & 15;             // i row within tile / c within c-block
  const int kg = lane >> 4;              // k-group 0..3
  const int shamt = kg * 8;

  // ft element base (jt0 = p*64 + (kg>>1), c = i_l, ni0 = (kg&1)*8)
  const unsigned short* ftb =
      ft + ((((size_t)b * 128 + p * 64 + (kg >> 1)) * 4 + h) * 64 + i_l) * 16 +
      (kg & 1) * 8;

  // ---- B prologue loads: issue BEFORE the barrier (global, no LDS dep) ----
  uint4 A0, A1, A2, A3, B0, B1, B2, B3;
#define LOADB(s, P0_, P1_, P2_, P3_)                               \
  {                                                                \
    const unsigned short* fp_ = ftb + (size_t)(s) * 8192;          \
    P0_ = *(const uint4*)(fp_);                                    \
    P1_ = *(const uint4*)(fp_ + 256);                              \
    P2_ = *(const uint4*)(fp_ + 512);                              \
    P3_ = *(const uint4*)(fp_ + 768);                              \
  }
  LOADB(0, A0, A1, A2, A3)
  LOADB(1, B0, B1, B2, B3)

  // ---- stage s_dst (32 KB contiguous) ----
  {
    const float4* src = (const float4*)(sdst + (size_t)b * 4 * 2048);
    float4* dst = (float4*)sd;
#pragma unroll
    for (int q = 0; q < 4; ++q) dst[tid + q * 512] = src[tid + q * 512];
  }
  // ---- stream adj rows i0..i0+15 (128 KB, once grid-wide) -> Aw[word][row] ----
  {
    const int* abase = adj + (size_t)b * 2048 * 2048 + (size_t)i0 * 2048;
    unsigned short* dst16 = (unsigned short*)Aw;
#pragma unroll
    for (int k = 0; k < 4; ++k) {
      const int idx = k * 512 + tid;          // [0,2048)
      const int r = idx >> 7;                 // row 0..15
      const int s16 = idx & 127;              // 16-col group
      const int4* ap = (const int4*)(abase + (size_t)r * 2048 + s16 * 16);
      int4 v0 = ap[0], v1 = ap[1], v2 = ap[2], v3 = ap[3];
      int vv[16] = {v0.x, v0.y, v0.z, v0.w, v1.x, v1.y, v1.z, v1.w,
                    v2.x, v2.y, v2.z, v2.w, v3.x, v3.y, v3.z, v3.w};
      unsigned m = 0;
#pragma unroll
      for (int i = 0; i < 16; ++i) m |= (vv[i] ? 1u : 0u) << i;
      dst16[((s16 >> 1) * 17 + r) * 2 + (s16 & 1)] = (unsigned short)m;
    }
  }
  const float si = ssrc[((size_t)b * 4 + h) * 2048 + i0 + i_l];
  const float* sdh = sd + h * 2048 + p * 1024 + kg * 8;

  f32x4 acc0, acc1, acc2, acc3;
#pragma unroll
  for (int q = 0; q < 4; ++q) { acc0[q] = 0.f; acc1[q] = 0.f; acc2[q] = 0.f; acc3[q] = 0.f; }
  float lsumA = 0.f, lsumB = 0.f;

  __syncthreads();

#define LOADM(s, mw_, t0_, t1_)                                    \
  {                                                                \
    mw_ = Aw[(p * 32 + (s)) * 17 + i_l];                           \
    const float* tp_ = sdh + (size_t)(s) * 32;                     \
    t0_ = *(const float4*)tp_;                                     \
    t1_ = *(const float4*)(tp_ + 4);                               \
  }

  // 8 independent exp chains -> depth-3 tree sum -> one lsum add
#define COMPE(mw_, t0_, t1_, af_, lsum_)                           \
  {                                                                \
    const unsigned byte_ = ((mw_) >> shamt) & 0xffu;               \
    float tj_[8] = {t0_.x, t0_.y, t0_.z, t0_.w,                    \
                    t1_.x, t1_.y, t1_.z, t1_.w};                   \
    float e_[8];                                                   \
    _Pragma("unroll")                                              \
    for (int q = 0; q < 8; ++q) {                                  \
      float x_ = si + tj_[q];                                      \
      float y_ = fmaxf(x_, 0.2f * x_);                             \
      float ev_ = __builtin_amdgcn_exp2f(y_);                      \
      e_[q] = (byte_ & (1u << q)) ? ev_ : 0.f;                     \
    }                                                              \
    float s01_ = e_[0] + e_[1], s23_ = e_[2] + e_[3];              \
    float s45_ = e_[4] + e_[5], s67_ = e_[6] + e_[7];              \
    lsum_ += (s01_ + s23_) + (s45_ + s67_);                        \
    _Pragma("unroll")                                              \
    for (int q2 = 0; q2 < 4; ++q2) {                               \
      unsigned r_;                                                 \
      asm("v_cvt_pk_bf16_f32 %0, %1, %2"                           \
          : "=v"(r_) : "v"(e_[2 * q2]), "v"(e_[2 * q2 + 1]));      \
      af_.u[q2] = r_;                                              \
    }                                                              \
  }

#define DOMFMA(af_, P0_, P1_, P2_, P3_)                            \
  {                                                                \
    BB bb_;                                                        \
    bb_.q = P0_;                                                   \
    acc0 = __builtin_amdgcn_mfma_f32_16x16x32_bf16(af_.v, bb_.v, acc0, 0, 0, 0); \
    bb_.q = P1_;                                                   \
    acc1 = __builtin_amdgcn_mfma_f32_16x16x32_bf16(af_.v, bb_.v, acc1, 0, 0, 0); \
    bb_.q = P2_;                                                   \
    acc2 = __builtin_amdgcn_mfma_f32_16x16x32_bf16(af_.v, bb_.v, acc2, 0, 0, 0); \
    bb_.q = P3_;                                                   \
    acc3 = __builtin_amdgcn_mfma_f32_16x16x32_bf16(af_.v, bb_.v, acc3, 0, 0, 0); \
  }

  unsigned mwA, mwB;
  float4 ta0, ta1, tb0, tb1;
  LOADM(0, mwA, ta0, ta1)

  for (int s = 0; s < 32; s += 2) {
    // ---- stage A: step s ----
    LOADM(s + 1, mwB, tb0, tb1)
    AF afA;
    COMPE(mwA, ta0, ta1, afA, lsumA)
    DOMFMA(afA, A0, A1, A2, A3)
    {
      const int sn = (s + 2 < 32) ? s + 2 : 31;
      LOADB(sn, A0, A1, A2, A3)
    }
    // ---- stage B: step s+1 ----
    {
      const int sm = (s + 2 < 32) ? s + 2 : 31;
      LOADM(sm, mwA, ta0, ta1)
    }
    AF afB;
    COMPE(mwB, tb0, tb1, afB, lsumB)
    DOMFMA(afB, B0, B1, B2, B3)
    {
      const int sn = (s + 3 < 32) ? s + 3 : 31;
      LOADB(sn, B0, B1, B2, B3)
    }
  }
#undef LOADB
#undef LOADM
#undef COMPE
#undef DOMFMA

  float lsum = lsumA + lsumB;

  // ---- epilogue: fold k-groups, combine p=0/p=1, normalize, store ----
  float lsum2 = lsum + __shfl_xor(lsum, 16);
  lsum2 += __shfl_xor(lsum2, 32);               // per-i, this p-half's sum
  float* ep = (float*)lds;                      // [4][16][64] f32 = 16 KB
  float* el = (float*)(lds + 16384);            // [4][16] f32
  __syncthreads();                              // done reading sd/Aw
  if (p == 1) {
#pragma unroll
    for (int r = 0; r < 4; ++r) {
      const int row = kg * 4 + r;
      ep[(h * 16 + row) * 64 + 0  + i_l] = acc0[r];
      ep[(h * 16 + row) * 64 + 16 + i_l] = acc1[r];
      ep[(h * 16 + row) * 64 + 32 + i_l] = acc2[r];
      ep[(h * 16 + row) * 64 + 48 + i_l] = acc3[r];
    }
    if (lane < 16) el[h * 16 + lane] = lsum2;
  }
  __syncthreads();
  if (p == 0) {
    const float L = lsum2 + el[h * 16 + i_l];
    const float rinv = 1.0f / L;
    float* ob = out + ((size_t)(b * 2048 + i0)) * 256 + h * 64;
#pragma unroll
    for (int r = 0; r < 4; ++r) {
      const int row = kg * 4 + r;
      const float ri = __shfl(rinv, row);
      ob[(size_t)row * 256 + 0  + i_l] = (acc0[r] + ep[(h * 16 + row) * 64 + 0  + i_l]) * ri;
      ob[(size_t)row * 256 + 16 + i_l] = (acc1[r] + ep[(h * 16 + row) * 64 + 16 + i_l]) * ri;
      ob[(size_t)row * 256 + 32 + i_l] = (acc2[r] + ep[(h * 16 + row) * 64 + 32 + i_l]) * ri;
      ob[(size_t)row * 256 + 48 + i_l] = (acc3[r] + ep[(h * 16 + row) * 64 + 48 + i_l]) * ri;
    }
  }
}

// ---------------------------------------------------------------------------
extern "C" void kernel_launch(void* const* d_in, const int* in_sizes, int n_in,
                              void* d_out, int out_size, void* d_ws, size_t ws_size,
                              hipStream_t stream) {
  const float* X    = (const float*)d_in[0];   // (8,2048,256) f32
  const int*   adj  = (const int*)d_in[1];     // (8,2048,2048) i32
  const float* W    = (const float*)d_in[2];   // (256,256) f32
  const float* bias = (const float*)d_in[3];   // (256,) f32
  const float* a    = (const float*)d_in[4];   // (4,128) f32
  float* out = (float*)d_out;

  unsigned short* ft = (unsigned short*)d_ws;                    // 8 MB bf16
  float* ssrc = (float*)((char*)d_ws + 8388608);                 // 256 KB
  float* sdst = ssrc + 8 * 4 * 2048;                             // 256 KB

  gat_k1<<<dim3(128, 2, 1), 256, 0, stream>>>(X, W, bias, a, ft, ssrc, sdst);
  gat_k2<<<dim3(1024, 1, 1), 512, 0, stream>>>(adj, ft, ssrc, sdst, out);
}

// Round 8
// 104.645 us; speedup vs baseline: 1.0185x; 1.0185x over previous
//
#include <hip/hip_runtime.h>

#define LOG2E 1.4426950408889634f

typedef __attribute__((ext_vector_type(8))) short bf16x8;
typedef __attribute__((ext_vector_type(4))) float f32x4;

union AF { unsigned u[4]; bf16x8 v; };

__device__ __forceinline__ unsigned short f2bf(float f) {
  unsigned int u = __float_as_uint(f);
  u = (u + 0x7fffu + ((u >> 16) & 1u)) >> 16;   // RNE, finite inputs only
  return (unsigned short)u;
}

// ---------------------------------------------------------------------------
// Kernel 1: f = X @ W^T + b  (fp32 SGEMM, 128x128 tile, 8x8/thread)
// Emits: ft (bf16, layout [b][n/16][h][c][n%16]) and s_src/s_dst ([b][h][n],
// f32, PRE-SCALED by log2(e) so k2 can use raw v_exp_f32).
// ---------------------------------------------------------------------------
__global__ __launch_bounds__(256) void gat_k1(
    const float* __restrict__ X, const float* __restrict__ W,
    const float* __restrict__ bias, const float* __restrict__ a,
    unsigned short* __restrict__ ft, float* __restrict__ ssrc,
    float* __restrict__ sdst)
{
  __shared__ float Xs[8][128];
  __shared__ float Ws[8][128];
  const int tid = threadIdx.x;
  const int tx = tid & 15, ty = tid >> 4;
  const int m0 = blockIdx.x * 128;
  const int c0 = blockIdx.y * 128;

  float acc[8][8];
#pragma unroll
  for (int r = 0; r < 8; ++r)
#pragma unroll
    for (int j = 0; j < 8; ++j) acc[r][j] = 0.f;

  const int lrow = tid >> 1;
  const int kk0 = (tid & 1) * 4;
  const float* Xp = X + (size_t)(m0 + lrow) * 256 + kk0;
  const float* Wp = W + (size_t)(c0 + lrow) * 256 + kk0;

  for (int kc = 0; kc < 256; kc += 8) {
    float4 xv = *(const float4*)(Xp + kc);
    float4 wv = *(const float4*)(Wp + kc);
    __syncthreads();
    Xs[kk0 + 0][lrow] = xv.x; Xs[kk0 + 1][lrow] = xv.y;
    Xs[kk0 + 2][lrow] = xv.z; Xs[kk0 + 3][lrow] = xv.w;
    Ws[kk0 + 0][lrow] = wv.x; Ws[kk0 + 1][lrow] = wv.y;
    Ws[kk0 + 2][lrow] = wv.z; Ws[kk0 + 3][lrow] = wv.w;
    __syncthreads();
#pragma unroll
    for (int kk = 0; kk < 8; ++kk) {
      float av[8], wv8[8];
#pragma unroll
      for (int r = 0; r < 8; ++r) av[r] = Xs[kk][ty * 8 + r];
#pragma unroll
      for (int j = 0; j < 8; ++j) wv8[j] = Ws[kk][tx * 8 + j];
#pragma unroll
      for (int r = 0; r < 8; ++r)
#pragma unroll
        for (int j = 0; j < 8; ++j) acc[r][j] = fmaf(av[r], wv8[j], acc[r][j]);
    }
  }

  const int b = m0 >> 11;
  const int nloc0 = (m0 & 2047) + ty * 8;
  const int cg0 = c0 + tx * 8;
  const int h = cg0 >> 6;
  const int cb = cg0 & 63;

  float bv[8], av_s[8], av_d[8];
#pragma unroll
  for (int j = 0; j < 8; ++j) {
    bv[j]   = bias[cg0 + j];
    av_s[j] = a[h * 128 + cb + j];
    av_d[j] = a[h * 128 + 64 + cb + j];
  }
#pragma unroll
  for (int r = 0; r < 8; ++r)
#pragma unroll
    for (int j = 0; j < 8; ++j) acc[r][j] += bv[j];

  const int jt = nloc0 >> 4;
  const int ni = nloc0 & 15;
#pragma unroll
  for (int j = 0; j < 8; ++j) {
    unsigned int u[4];
#pragma unroll
    for (int q = 0; q < 4; ++q) {
      unsigned int lo = f2bf(acc[2 * q + 0][j]);
      unsigned int hi = f2bf(acc[2 * q + 1][j]);
      u[q] = lo | (hi << 16);
    }
    size_t off = ((((size_t)b * 128 + jt) * 4 + h) * 64 + (cb + j)) * 16 + ni;
    *(uint4*)(ft + off) = make_uint4(u[0], u[1], u[2], u[3]);
  }

  float sp[8], dp[8];
#pragma unroll
  for (int r = 0; r < 8; ++r) {
    float s = 0.f, d = 0.f;
#pragma unroll
    for (int j = 0; j < 8; ++j) {
      s = fmaf(acc[r][j], av_s[j], s);
      d = fmaf(acc[r][j], av_d[j], d);
    }
    sp[r] = s; dp[r] = d;
  }
#pragma unroll
  for (int off = 1; off < 8; off <<= 1) {
#pragma unroll
    for (int r = 0; r < 8; ++r) {
      sp[r] += __shfl_xor(sp[r], off);
      dp[r] += __shfl_xor(dp[r], off);
    }
  }
  if ((tx & 7) == 0) {
    float* sb = ssrc + ((size_t)b * 4 + h) * 2048 + nloc0;
    float* db = sdst + ((size_t)b * 4 + h) * 2048 + nloc0;
#pragma unroll
    for (int r = 0; r < 8; ++r) { sb[r] = sp[r] * LOG2E; db[r] = dp[r] * LOG2E; }
  }
}

// ---------------------------------------------------------------------------
// Kernel 2: fused mask + leaky-relu + softmax + PV (bf16 MFMA 16x16x32)
// Grid 1024 blocks (b = idx&7 XCD-pinned, itile = idx>>3, 16 i-rows).
// 512 thr = 8 waves = (head h, j-half p). 32 steps of 32 j's per wave.
// This round: pointer-increment addressing (no per-step addr math),
// direct bf16x8 loads as MFMA operands (no union movs), row-sum via a 5th
// MFMA against a ones matrix (shuffle-free 1/L), peeled tail (no clamps),
// launch_bounds(512,6) for 3 blocks/CU with 2-deep prefetch register room.
// ---------------------------------------------------------------------------
__global__ __launch_bounds__(512, 6) void gat_k2(
    const int* __restrict__ adj, const unsigned short* __restrict__ ft,
    const float* __restrict__ ssrc, const float* __restrict__ sdst,
    float* __restrict__ out)
{
  __shared__ __align__(16) unsigned char lds[37120];  // sd 32KB | Aw [64][17] u32
  float* sd = (float*)lds;                            // [4][2048] f32
  unsigned* Aw = (unsigned*)(lds + 32768);            // [64][17] u32

  const int tid = threadIdx.x;
  const int b = blockIdx.x & 7;
  const int itile = blockIdx.x >> 3;     // 0..127
  const int i0 = itile * 16;
  const int w = tid >> 6;
  const int h = w >> 1;                  // head
  const int p = w & 1;                   // j-half
  const int lane = tid & 63;
  const int i_l = lane & 15;             // i row within tile / c within c-block
  const int kg = lane >> 4;              // k-group 0..3
  const int shamt = kg * 8;

  // ---- ft pointer (bf16x8 units): step stride 1024, cb stride 32 ----
  const bf16x8* fp = (const bf16x8*)ft +
      ((((size_t)b * 128 + p * 64 + (kg >> 1)) * 4 + h) * 64 + i_l) * 2 +
      (kg & 1);

  // ---- prologue B-frag prefetch: issue BEFORE LDS staging (T14) ----
  bf16x8 A0 = fp[0], A1 = fp[32], A2 = fp[64], A3 = fp[96];
  fp += 1024;
  bf16x8 B0 = fp[0], B1 = fp[32], B2 = fp[64], B3 = fp[96];
  fp += 1024;

  // ---- stage s_dst (32 KB contiguous) ----
  {
    const float4* src = (const float4*)(sdst + (size_t)b * 4 * 2048);
    float4* dst = (float4*)sd;
#pragma unroll
    for (int q = 0; q < 4; ++q) dst[tid + q * 512] = src[tid + q * 512];
  }
  // ---- stream adj rows i0..i0+15 (128 KB, once grid-wide) -> Aw[word][row] ----
  {
    const int* abase = adj + (size_t)b * 2048 * 2048 + (size_t)i0 * 2048;
    unsigned short* dst16 = (unsigned short*)Aw;
#pragma unroll
    for (int k = 0; k < 4; ++k) {
      const int idx = k * 512 + tid;          // [0,2048)
      const int r = idx >> 7;                 // row 0..15
      const int s16 = idx & 127;              // 16-col group
      const int4* ap = (const int4*)(abase + (size_t)r * 2048 + s16 * 16);
      int4 v0 = ap[0], v1 = ap[1], v2 = ap[2], v3 = ap[3];
      int vv[16] = {v0.x, v0.y, v0.z, v0.w, v1.x, v1.y, v1.z, v1.w,
                    v2.x, v2.y, v2.z, v2.w, v3.x, v3.y, v3.z, v3.w};
      unsigned m = 0;
#pragma unroll
      for (int i = 0; i < 16; ++i) m |= (vv[i] ? 1u : 0u) << i;
      dst16[((s16 >> 1) * 17 + r) * 2 + (s16 & 1)] = (unsigned short)m;
    }
  }
  const float si = ssrc[((size_t)b * 4 + h) * 2048 + i0 + i_l];

  // induction pointers for mask word and s_dst slice
  const unsigned* awp = Aw + (p * 32) * 17 + i_l;
  const float* sdp = sd + h * 2048 + p * 1024 + kg * 8;

  f32x4 acc0, acc1, acc2, acc3, acc4;
#pragma unroll
  for (int q = 0; q < 4; ++q) {
    acc0[q] = 0.f; acc1[q] = 0.f; acc2[q] = 0.f; acc3[q] = 0.f; acc4[q] = 0.f;
  }
  bf16x8 ones;
#pragma unroll
  for (int q = 0; q < 8; ++q) ones[q] = (short)0x3F80;  // bf16 1.0

  __syncthreads();

  // compute e's, pack to bf16, run 4 PV MFMAs + 1 row-sum MFMA
#define STEP(mw_, t0_, t1_, F0_, F1_, F2_, F3_)                    \
  {                                                                \
    const unsigned byte_ = ((mw_) >> shamt) & 0xffu;               \
    float tj_[8] = {t0_.x, t0_.y, t0_.z, t0_.w,                    \
                    t1_.x, t1_.y, t1_.z, t1_.w};                   \
    float e_[8];                                                   \
    _Pragma("unroll")                                              \
    for (int q = 0; q < 8; ++q) {                                  \
      float x_ = si + tj_[q];                                      \
      float y_ = fmaxf(x_, 0.2f * x_);                             \
      float ev_ = __builtin_amdgcn_exp2f(y_);                      \
      e_[q] = (byte_ & (1u << q)) ? ev_ : 0.f;                     \
    }                                                              \
    AF af_;                                                        \
    _Pragma("unroll")                                              \
    for (int q2 = 0; q2 < 4; ++q2) {                               \
      unsigned r_;                                                 \
      asm("v_cvt_pk_bf16_f32 %0, %1, %2"                           \
          : "=v"(r_) : "v"(e_[2 * q2]), "v"(e_[2 * q2 + 1]));      \
      af_.u[q2] = r_;                                              \
    }                                                              \
    acc0 = __builtin_amdgcn_mfma_f32_16x16x32_bf16(af_.v, F0_, acc0, 0, 0, 0); \
    acc1 = __builtin_amdgcn_mfma_f32_16x16x32_bf16(af_.v, F1_, acc1, 0, 0, 0); \
    acc2 = __builtin_amdgcn_mfma_f32_16x16x32_bf16(af_.v, F2_, acc2, 0, 0, 0); \
    acc3 = __builtin_amdgcn_mfma_f32_16x16x32_bf16(af_.v, F3_, acc3, 0, 0, 0); \
    acc4 = __builtin_amdgcn_mfma_f32_16x16x32_bf16(af_.v, ones, acc4, 0, 0, 0); \
  }

  unsigned mwA, mwB;
  float4 ta0, ta1, tb0, tb1;
  mwA = awp[0];
  ta0 = *(const float4*)sdp;
  ta1 = *(const float4*)(sdp + 4);
  awp += 17; sdp += 32;

  for (int s = 0; s < 30; s += 2) {
    // ---- stage A: step s ----
    mwB = awp[0];
    tb0 = *(const float4*)sdp;
    tb1 = *(const float4*)(sdp + 4);
    awp += 17; sdp += 32;
    STEP(mwA, ta0, ta1, A0, A1, A2, A3)
    A0 = fp[0]; A1 = fp[32]; A2 = fp[64]; A3 = fp[96];   // prefetch s+2
    fp += 1024;
    // ---- stage B: step s+1 ----
    mwA = awp[0];
    ta0 = *(const float4*)sdp;
    ta1 = *(const float4*)(sdp + 4);
    awp += 17; sdp += 32;
    STEP(mwB, tb0, tb1, B0, B1, B2, B3)
    B0 = fp[0]; B1 = fp[32]; B2 = fp[64]; B3 = fp[96];   // prefetch s+3
    fp += 1024;
  }
  // ---- tail: steps 30 (A) and 31 (B), no prefetch ----
  mwB = awp[0];
  tb0 = *(const float4*)sdp;
  tb1 = *(const float4*)(sdp + 4);
  STEP(mwA, ta0, ta1, A0, A1, A2, A3)
  STEP(mwB, tb0, tb1, B0, B1, B2, B3)
#undef STEP

  // ---- epilogue: combine p=0/p=1 partials, normalize, store ----
  // acc4[r] = sum_j e for row kg*4+r (same rows as acc0..3) -> no shuffles.
  float* ep = (float*)lds;                      // [4][16][64] f32 = 16 KB
  float* el = (float*)(lds + 16384);            // [4][16] f32
  __syncthreads();                              // done reading sd/Aw
  if (p == 1) {
#pragma unroll
    for (int r = 0; r < 4; ++r) {
      const int row = kg * 4 + r;
      ep[(h * 16 + row) * 64 + 0  + i_l] = acc0[r];
      ep[(h * 16 + row) * 64 + 16 + i_l] = acc1[r];
      ep[(h * 16 + row) * 64 + 32 + i_l] = acc2[r];
      ep[(h * 16 + row) * 64 + 48 + i_l] = acc3[r];
    }
    if (i_l == 0) {
#pragma unroll
      for (int r = 0; r < 4; ++r) el[h * 16 + kg * 4 + r] = acc4[r];
    }
  }
  __syncthreads();
  if (p == 0) {
    float* ob = out + ((size_t)(b * 2048 + i0)) * 256 + h * 64;
#pragma unroll
    for (int r = 0; r < 4; ++r) {
      const int row = kg * 4 + r;
      const float L = acc4[r] + el[h * 16 + row];
      const float ri = 1.0f / L;
      ob[(size_t)row * 256 + 0  + i_l] = (acc0[r] + ep[(h * 16 + row) * 64 + 0  + i_l]) * ri;
      ob[(size_t)row * 256 + 16 + i_l] = (acc1[r] + ep[(h * 16 + row) * 64 + 16 + i_l]) * ri;
      ob[(size_t)row * 256 + 32 + i_l] = (acc2[r] + ep[(h * 16 + row) * 64 + 32 + i_l]) * ri;
      ob[(size_t)row * 256 + 48 + i_l] = (acc3[r] + ep[(h * 16 + row) * 64 + 48 + i_l]) * ri;
    }
  }
}

// ---------------------------------------------------------------------------
extern "C" void kernel_launch(void* const* d_in, const int* in_sizes, int n_in,
                              void* d_out, int out_size, void* d_ws, size_t ws_size,
                              hipStream_t stream) {
  const float* X    = (const float*)d_in[0];   // (8,2048,256) f32
  const int*   adj  = (const int*)d_in[1];     // (8,2048,2048) i32
  const float* W    = (const float*)d_in[2];   // (256,256) f32
  const float* bias = (const float*)d_in[3];   // (256,) f32
  const float* a    = (const float*)d_in[4];   // (4,128) f32
  float* out = (float*)d_out;

  unsigned short* ft = (unsigned short*)d_ws;                    // 8 MB bf16
  float* ssrc = (float*)((char*)d_ws + 8388608);                 // 256 KB
  float* sdst = ssrc + 8 * 4 * 2048;                             // 256 KB

  gat_k1<<<dim3(128, 2, 1), 256, 0, stream>>>(X, W, bias, a, ft, ssrc, sdst);
  gat_k2<<<dim3(1024, 1, 1), 512, 0, stream>>>(adj, ft, ssrc, sdst, out);
}